// Round 6
// baseline (1904.890 us; speedup 1.0000x reference)
//
#include <hip/hip_runtime.h>

// Neural HMM forward-algorithm NLL.  K=128, V=50257, D=H=128, B=64, T=2048.
//
//  K1 k_emis : E[v][k] = exp(tag[k]·word[v] + bias[v]) (unnormalized) + partial Z
//  K2 k_trans: A2[i][j] = softmax_j(Wq+b)[i][j] / Z_j ; piZ / piZP (permuted)
//  K3 k_gather: emP[t][b][p] = bf16( E[tok[b,t]][phi^-1(p)] * bump(t) )
//  K4 k_fwd_m3: barrier-free MFMA recursion, TWO independent 16-batch chains
//     interleaved per wave (fills dependency-stall cycles with the other
//     chain's instructions). 2 blocks x 64 threads cover all 64 batches.
//     State relabeling phi (j=64h+16c+4g+r -> p=32c+8g+4h+r) makes the MFMA
//     D-fragment exactly the next step's B-fragment lane-locally: alpha never
//     leaves registers; A2/em/piZ are pre-permuted.
//  K5 k_final : out = -sum_b ll[b]

#define KK 128
#define TT 2048
#define BB 64

typedef short v8s __attribute__((ext_vector_type(8)));
typedef float v4f __attribute__((ext_vector_type(4)));

__device__ __forceinline__ float wave_sum64(float v) {
#pragma unroll
  for (int m = 32; m; m >>= 1) v += __shfl_xor(v, m, 64);
  return v;
}
__device__ __forceinline__ float wave_max64(float v) {
#pragma unroll
  for (int m = 32; m; m >>= 1) v = fmaxf(v, __shfl_xor(v, m, 64));
  return v;
}
// f32 -> bf16 round-to-nearest-even (positive normals here)
__device__ __forceinline__ unsigned short f2bf(float x) {
  union { float f; unsigned u; } c; c.f = x;
  unsigned r = c.u + 0x7fffu + ((c.u >> 16) & 1u);
  return (unsigned short)(r >> 16);
}
__device__ __forceinline__ float bflo(unsigned u) {
  union { unsigned u; float f; } c; c.u = u << 16; return c.f;
}
__device__ __forceinline__ float bfhi(unsigned u) {
  union { unsigned u; float f; } c; c.u = u & 0xffff0000u; return c.f;
}
// pack two f32 -> two bf16 in one u32 (dst.lo = bf16(a), dst.hi = bf16(b))
__device__ __forceinline__ unsigned cvtpk(float a, float b) {
  unsigned r;
  asm("v_cvt_pk_bf16_f32 %0, %1, %2" : "=v"(r) : "v"(a), "v"(b));
  return r;
}
__device__ __forceinline__ v8s mk8(unsigned a, unsigned b, unsigned c, unsigned d) {
  union { uint4 u; v8s s; } x;
  x.u = make_uint4(a, b, c, d);
  return x.s;
}

// ---------------- K1: emission table E (V x K) + partial Z ----------------
__global__ __launch_bounds__(128, 1)
void k_emis(const float* __restrict__ tag, const float* __restrict__ word,
            const float* __restrict__ bias, float* __restrict__ E,
            float* __restrict__ partialZ, int V) {
  __shared__ float4 wtile[128 * 32];
  __shared__ float btile[128];
  const int tid = threadIdx.x;
  const int v0 = blockIdx.x * 128;

  const float4* w4 = (const float4*)word;
  const int maxi = V * 32 - 1;
#pragma unroll
  for (int it = 0; it < 32; ++it) {
    int idx = it * 128 + tid;
    int g = v0 * 32 + idx;
    wtile[idx] = w4[min(g, maxi)];
  }
  btile[tid] = (v0 + tid < V) ? bias[v0 + tid] : 0.f;

  float treg[128];
  const float4* t4 = (const float4*)(tag + (size_t)tid * 128);
#pragma unroll
  for (int c = 0; c < 32; ++c) {
    float4 x = t4[c];
    treg[4 * c + 0] = x.x; treg[4 * c + 1] = x.y;
    treg[4 * c + 2] = x.z; treg[4 * c + 3] = x.w;
  }
  __syncthreads();

  float zp = 0.f;
  for (int v = 0; v < 128; ++v) {
    if (v0 + v >= V) break;  // uniform
    const float4* row = &wtile[v * 32];
    float a0 = 0.f, a1 = 0.f, a2 = 0.f, a3 = 0.f;
#pragma unroll
    for (int c = 0; c < 32; ++c) {
      float4 pv = row[c];
      a0 = fmaf(pv.x, treg[4 * c + 0], a0);
      a1 = fmaf(pv.y, treg[4 * c + 1], a1);
      a2 = fmaf(pv.z, treg[4 * c + 2], a2);
      a3 = fmaf(pv.w, treg[4 * c + 3], a3);
    }
    float e = __expf((a0 + a1) + (a2 + a3) + btile[v]);
    E[(size_t)(v0 + v) * KK + tid] = e;
    zp += e;
  }
  partialZ[(size_t)blockIdx.x * KK + tid] = zp;
}

// ---------------- K2: transition matrix A2 (K x K) + piZ + piZP ----------
__global__ __launch_bounds__(128)
void k_trans(const float* __restrict__ W, const float* __restrict__ q,
             const float* __restrict__ tb, const float* __restrict__ pZ,
             const float* __restrict__ initlog, float* __restrict__ A2,
             float* __restrict__ piZ, float* __restrict__ piZP, int nPart) {
  __shared__ float qs[KK];
  __shared__ float r0[2], r1[2];
  const int j = threadIdx.x, i = blockIdx.x;
  qs[j] = q[j];
  __syncthreads();

  const float4* w4 = (const float4*)(W + ((size_t)(i * KK + j)) * KK);
  const float4* q4 = (const float4*)qs;
  float a0 = 0.f, a1 = 0.f, a2 = 0.f, a3 = 0.f;
#pragma unroll
  for (int c = 0; c < KK / 4; ++c) {
    float4 wv = w4[c], qv = q4[c];
    a0 = fmaf(wv.x, qv.x, a0); a1 = fmaf(wv.y, qv.y, a1);
    a2 = fmaf(wv.z, qv.z, a2); a3 = fmaf(wv.w, qv.w, a3);
  }
  float logit = (a0 + a1) + (a2 + a3) + tb[i * KK + j];

  float m = wave_max64(logit);
  if ((j & 63) == 0) r0[j >> 6] = m;
  __syncthreads();
  m = fmaxf(r0[0], r0[1]);
  float e = __expf(logit - m);
  float s = wave_sum64(e);
  if ((j & 63) == 0) r1[j >> 6] = s;
  __syncthreads();
  s = r1[0] + r1[1];

  float Z0 = 0.f, Z1 = 0.f, Z2 = 0.f, Z3 = 0.f;
  float Z4 = 0.f, Z5 = 0.f, Z6 = 0.f, Z7 = 0.f;
  int p = 0;
  for (; p + 8 <= nPart; p += 8) {
    Z0 += pZ[(size_t)(p + 0) * KK + j]; Z1 += pZ[(size_t)(p + 1) * KK + j];
    Z2 += pZ[(size_t)(p + 2) * KK + j]; Z3 += pZ[(size_t)(p + 3) * KK + j];
    Z4 += pZ[(size_t)(p + 4) * KK + j]; Z5 += pZ[(size_t)(p + 5) * KK + j];
    Z6 += pZ[(size_t)(p + 6) * KK + j]; Z7 += pZ[(size_t)(p + 7) * KK + j];
  }
  for (; p < nPart; ++p) Z0 += pZ[(size_t)p * KK + j];
  float Z = ((Z0 + Z1) + (Z2 + Z3)) + ((Z4 + Z5) + (Z6 + Z7));

  A2[i * KK + j] = e / (s * Z);

  if (i == 0) {
    float x = initlog[j];
    __syncthreads();
    float m2 = wave_max64(x);
    if ((j & 63) == 0) r0[j >> 6] = m2;
    __syncthreads();
    m2 = fmaxf(r0[0], r0[1]);
    float e2 = __expf(x - m2);
    float s2 = wave_sum64(e2);
    if ((j & 63) == 0) r1[j >> 6] = s2;
    __syncthreads();
    s2 = r1[0] + r1[1];
    float v = e2 / (s2 * Z);
    piZ[j] = v;
    // phi(j): j = 64h+16c+4g+r -> p = 32c+8g+4h+r
    int pp = 32 * ((j >> 4) & 3) + 8 * ((j >> 2) & 3) + 4 * (j >> 6) + (j & 3);
    piZP[pp] = v;
  }
}

// ---------------- K3: em gather, PERMUTED layout ----------------
__global__ __launch_bounds__(128, 1)
void k_gather(const int* __restrict__ toks, const float* __restrict__ E,
              unsigned* __restrict__ em) {
  const int b = blockIdx.x;        // 0..63
  const int tc = blockIdx.y;       // 0..63 (32 t's each)
  const int q = threadIdx.x & 63;
  const int half = threadIdx.x >> 6;
  const int perm = 32 * ((q >> 1) & 1) + 8 * (q >> 4) + 2 * ((q >> 2) & 3) + (q & 1);
  const float2* E2 = (const float2*)E;
#pragma unroll 4
  for (int it = 0; it < 16; ++it) {
    int t = tc * 32 + it * 2 + half;
    int tok = toks[(size_t)b * TT + t];
    float2 v = E2[(size_t)tok * 64 + perm];
    float sc = ((t & 3) == 0 && (t & 63) != 0) ? 0x1p64f : 1.0f;
    unsigned lo = f2bf(v.x * sc), hi = f2bf(v.y * sc);
    em[((size_t)t * BB + b) * 64 + q] = lo | (hi << 16);
  }
}

// ---------------- K4: dual-chain barrier-free MFMA recursion -------------
// 2 blocks x 64 threads. lane l: b=l&15, g=l>>4. Chain A = batches
// [32*blk, +16), chain B = [32*blk+16, +16). Both chains share the static
// af fragments (AGPR-pinned); their MFMA chains + epilogues interleave to
// fill dependency stalls.
template <int S>
__device__ __forceinline__ void hmm_step2(
    int t, const unsigned* __restrict__ emLa, const unsigned* __restrict__ emLb,
    const v8s (&af)[8][4], v8s (&bfa)[4], v8s (&bfb)[4],
    uint4 (&emQa)[2][4], uint4 (&emQb)[2][4],
    float& La, float& Lb, const v4f& ZED) {
  v4f acca[8], accb[8];
#pragma unroll
  for (int jt = 0; jt < 8; ++jt)
    acca[jt] = __builtin_amdgcn_mfma_f32_16x16x32_bf16(af[jt][0], bfa[0], ZED, 0, 0, 0);
#pragma unroll
  for (int jt = 0; jt < 8; ++jt)
    accb[jt] = __builtin_amdgcn_mfma_f32_16x16x32_bf16(af[jt][0], bfb[0], ZED, 0, 0, 0);
#pragma unroll
  for (int kc = 1; kc < 4; ++kc) {
#pragma unroll
    for (int jt = 0; jt < 8; ++jt)
      acca[jt] = __builtin_amdgcn_mfma_f32_16x16x32_bf16(af[jt][kc], bfa[kc], acca[jt], 0, 0, 0);
#pragma unroll
    for (int jt = 0; jt < 8; ++jt)
      accb[jt] = __builtin_amdgcn_mfma_f32_16x16x32_bf16(af[jt][kc], bfb[kc], accb[jt], 0, 0, 0);
  }

  uint4 eva[4], evb[4];
#pragma unroll
  for (int kc = 0; kc < 4; ++kc) { eva[kc] = emQa[S][kc]; evb[kc] = emQb[S][kc]; }
  {
    size_t tp = (t + 2 < TT) ? (size_t)(t + 2) : (size_t)(TT - 1);
#pragma unroll
    for (int kc = 0; kc < 4; ++kc) {
      emQa[S][kc] = *(const uint4*)(emLa + tp * 4096 + 16 * kc);
      emQb[S][kc] = *(const uint4*)(emLb + tp * 4096 + 16 * kc);
    }
  }

  float na[8][4], nb[8][4];
#pragma unroll
  for (int jt = 0; jt < 8; ++jt) {
    const int kc = jt & 3;
    unsigned qa0 = (jt < 4) ? eva[kc].x : eva[kc].z;
    unsigned qa1 = (jt < 4) ? eva[kc].y : eva[kc].w;
    na[jt][0] = acca[jt][0] * bflo(qa0);
    na[jt][1] = acca[jt][1] * bfhi(qa0);
    na[jt][2] = acca[jt][2] * bflo(qa1);
    na[jt][3] = acca[jt][3] * bfhi(qa1);
    unsigned qb0 = (jt < 4) ? evb[kc].x : evb[kc].z;
    unsigned qb1 = (jt < 4) ? evb[kc].y : evb[kc].w;
    nb[jt][0] = accb[jt][0] * bflo(qb0);
    nb[jt][1] = accb[jt][1] * bfhi(qb0);
    nb[jt][2] = accb[jt][2] * bflo(qb1);
    nb[jt][3] = accb[jt][3] * bfhi(qb1);
  }

  if ((t & 63) == 0) {  // true normalize every 64 steps (uniform branch)
    float sa = 0.f, sb = 0.f;
#pragma unroll
    for (int jt = 0; jt < 8; ++jt) {
      sa += (na[jt][0] + na[jt][1]) + (na[jt][2] + na[jt][3]);
      sb += (nb[jt][0] + nb[jt][1]) + (nb[jt][2] + nb[jt][3]);
    }
    sa += __shfl_xor(sa, 16, 64); sa += __shfl_xor(sa, 32, 64);
    sb += __shfl_xor(sb, 16, 64); sb += __shfl_xor(sb, 32, 64);
    float ra = __builtin_amdgcn_rcpf(sa);
    float rb = __builtin_amdgcn_rcpf(sb);
    La += __logf(sa);
    Lb += __logf(sb);
#pragma unroll
    for (int jt = 0; jt < 8; ++jt) {
      na[jt][0] *= ra; na[jt][1] *= ra; na[jt][2] *= ra; na[jt][3] *= ra;
      nb[jt][0] *= rb; nb[jt][1] *= rb; nb[jt][2] *= rb; nb[jt][3] *= rb;
    }
  }

#pragma unroll
  for (int kc = 0; kc < 4; ++kc) {
    bfa[kc] = mk8(cvtpk(na[kc][0], na[kc][1]), cvtpk(na[kc][2], na[kc][3]),
                  cvtpk(na[kc + 4][0], na[kc + 4][1]),
                  cvtpk(na[kc + 4][2], na[kc + 4][3]));
    bfb[kc] = mk8(cvtpk(nb[kc][0], nb[kc][1]), cvtpk(nb[kc][2], nb[kc][3]),
                  cvtpk(nb[kc + 4][0], nb[kc + 4][1]),
                  cvtpk(nb[kc + 4][2], nb[kc + 4][3]));
  }
}

__global__ __launch_bounds__(64, 1)
void k_fwd_m3(const unsigned* __restrict__ em, const float* __restrict__ A2,
              const float* __restrict__ piZP, float* __restrict__ ll) {
  const int l = threadIdx.x;
  const int b = l & 15;
  const int g = l >> 4;
  const int m = l & 15;
  const int gbA = blockIdx.x * 32 + b;
  const int gbB = blockIdx.x * 32 + 16 + b;

  // static A2 fragments (permuted on both axes); pin to AGPRs (blocks remat,
  // keeps arch-VGPR pressure low; MFMA reads AGPR A-operands directly)
  v8s af[8][4];
#pragma unroll
  for (int jt = 0; jt < 8; ++jt) {
    const int colj = 64 * (jt >> 2) + 16 * (jt & 3) + 4 * (m >> 2) + (m & 3);
#pragma unroll
    for (int kc = 0; kc < 4; ++kc) {
      v8s f;
#pragma unroll
      for (int e = 0; e < 8; ++e) {
        int row = 64 * (e >> 2) + 16 * kc + 4 * g + (e & 3);
        f[e] = (short)f2bf(A2[row * KK + colj]);
      }
      asm volatile("" : "+a"(f));  // steer to AGPR, block rematerialization
      af[jt][kc] = f;
    }
  }

  const unsigned* emLa = em + (size_t)gbA * 64 + 4 * g;
  const unsigned* emLb = em + (size_t)gbB * 64 + 4 * g;
  const v4f ZED = {0.f, 0.f, 0.f, 0.f};
  float La = 0.f, Lb = 0.f;

  // alphaP0 = piZP * em0  -> initial B-fragments, both chains
  v8s bfa[4], bfb[4];
#pragma unroll
  for (int kc = 0; kc < 4; ++kc) {
    float4 pz0 = *(const float4*)(piZP + 32 * kc + 8 * g);
    float4 pz1 = *(const float4*)(piZP + 32 * kc + 8 * g + 4);
    uint4 ea = *(const uint4*)(emLa + 16 * kc);
    bfa[kc] = mk8(cvtpk(pz0.x * bflo(ea.x), pz0.y * bfhi(ea.x)),
                  cvtpk(pz0.z * bflo(ea.y), pz0.w * bfhi(ea.y)),
                  cvtpk(pz1.x * bflo(ea.z), pz1.y * bfhi(ea.z)),
                  cvtpk(pz1.z * bflo(ea.w), pz1.w * bfhi(ea.w)));
    uint4 eb = *(const uint4*)(emLb + 16 * kc);
    bfb[kc] = mk8(cvtpk(pz0.x * bflo(eb.x), pz0.y * bfhi(eb.x)),
                  cvtpk(pz0.z * bflo(eb.y), pz0.w * bfhi(eb.y)),
                  cvtpk(pz1.x * bflo(eb.z), pz1.y * bfhi(eb.z)),
                  cvtpk(pz1.z * bflo(eb.w), pz1.w * bfhi(eb.w)));
  }

  // preload em for t=1 (slot 1) and t=2 (slot 0)
  uint4 emQa[2][4], emQb[2][4];
#pragma unroll
  for (int tp = 1; tp <= 2; ++tp)
#pragma unroll
    for (int kc = 0; kc < 4; ++kc) {
      emQa[tp & 1][kc] = *(const uint4*)(emLa + (size_t)tp * 4096 + 16 * kc);
      emQb[tp & 1][kc] = *(const uint4*)(emLb + (size_t)tp * 4096 + 16 * kc);
    }

  // steps 1..2046 in pairs, then 2047 (S = t&1)
  for (int c = 0; c < (TT - 2) / 2; ++c) {
    hmm_step2<1>(1 + 2 * c, emLa, emLb, af, bfa, bfb, emQa, emQb, La, Lb, ZED);
    hmm_step2<0>(2 + 2 * c, emLa, emLb, af, bfa, bfb, emQa, emQb, La, Lb, ZED);
  }
  hmm_step2<1>(TT - 1, emLa, emLb, af, bfa, bfb, emQa, emQb, La, Lb, ZED);

  // final sum over each lane's 32 alpha values, both chains
  float sa = 0.f, sb = 0.f;
#pragma unroll
  for (int kc = 0; kc < 4; ++kc) {
    union { v8s s; uint4 u; } xa; xa.s = bfa[kc];
    sa += (bflo(xa.u.x) + bfhi(xa.u.x)) + (bflo(xa.u.y) + bfhi(xa.u.y));
    sa += (bflo(xa.u.z) + bfhi(xa.u.z)) + (bflo(xa.u.w) + bfhi(xa.u.w));
    union { v8s s; uint4 u; } xb; xb.s = bfb[kc];
    sb += (bflo(xb.u.x) + bfhi(xb.u.x)) + (bflo(xb.u.y) + bfhi(xb.u.y));
    sb += (bflo(xb.u.z) + bfhi(xb.u.z)) + (bflo(xb.u.w) + bfhi(xb.u.w));
  }
  sa += __shfl_xor(sa, 16, 64); sa += __shfl_xor(sa, 32, 64);
  sb += __shfl_xor(sb, 16, 64); sb += __shfl_xor(sb, 32, 64);
  const float RESCALE_C = (float)(30720.0 * 0.6931471805599453);
  if (l < 16) {
    ll[blockIdx.x * 32 + l]      = La + __logf(sa) - RESCALE_C;
    ll[blockIdx.x * 32 + 16 + l] = Lb + __logf(sb) - RESCALE_C;
  }
}

// ---------------- K4-fallback (round-3 path, used if ws too small) --------
__global__ __launch_bounds__(256, 1)
void k_fwd_fb(const int* __restrict__ toks, const float* __restrict__ E,
              const float* __restrict__ A2, const float* __restrict__ piZ,
              float* __restrict__ ll) {
  __shared__ float pb[2][KK];
  __shared__ float part[2 * KK];
  __shared__ int tk[TT];
  __shared__ float red[4];
  const int tid = threadIdx.x;
  const int j = tid & (KK - 1);
  const int h = tid >> 7;
  const int b = blockIdx.x;

  const int4* t4 = (const int4*)(toks + (size_t)b * TT);
  int4* l4 = (int4*)tk;
#pragma unroll
  for (int c = 0; c < TT / 4 / 256; ++c) l4[c * 256 + tid] = t4[c * 256 + tid];

  float Areg[64];
  {
    const float* Acol = A2 + (size_t)(h * 64) * KK + j;
#pragma unroll
    for (int i = 0; i < 64; ++i) Areg[i] = Acol[i * KK];
  }
  __syncthreads();

  const float* Ej = E + j;
  float eA = Ej[(size_t)tk[1] * KK];
  float eB = Ej[(size_t)tk[2] * KK];
  float eC = Ej[(size_t)tk[3] * KK];
  float eD = Ej[(size_t)tk[4] * KK];
  if (h == 0) pb[0][j] = piZ[j] * Ej[(size_t)tk[0] * KK];
  float Lacc = 0.f;
  __syncthreads();

  for (int t = 1; t < TT; ++t) {
    const float4* ph = (const float4*)&pb[(t - 1) & 1][h * 64];
    float a0 = 0.f, a1 = 0.f, a2 = 0.f, a3 = 0.f;
#pragma unroll
    for (int c = 0; c < 16; ++c) {
      float4 pv = ph[c];
      a0 = fmaf(pv.x, Areg[4 * c + 0], a0);
      a1 = fmaf(pv.y, Areg[4 * c + 1], a1);
      a2 = fmaf(pv.z, Areg[4 * c + 2], a2);
      a3 = fmaf(pv.w, Areg[4 * c + 3], a3);
    }
    part[2 * j + h] = (a0 + a1) + (a2 + a3);
    __syncthreads();

    float e = eA; eA = eB; eB = eC; eC = eD;
    int tn = tk[t + 4 < TT ? t + 4 : TT - 1];
    eD = Ej[(size_t)tn * KK];

    float np = 0.f;
    if (h == 0) {
      float2 pr = *(const float2*)&part[2 * j];
      np = (pr.x + pr.y) * e;
    }
    if ((t & 63) == 0) {
      float v = wave_sum64(np);
      if ((tid & 63) == 0) red[tid >> 6] = v;
      __syncthreads();
      float tot = (red[0] + red[1]) + (red[2] + red[3]);
      np *= __builtin_amdgcn_rcpf(tot);
      if (tid == 0) Lacc += __logf(tot);
    } else if ((t & 3) == 0) {
      np *= 0x1p64f;
    }
    if (h == 0) pb[t & 1][j] = np;
    __syncthreads();
  }

  float lv = (h == 0) ? pb[(TT - 1) & 1][j] : 0.f;
  float v = wave_sum64(lv);
  if ((tid & 63) == 0) red[tid >> 6] = v;
  __syncthreads();
  float tot = (red[0] + red[1]) + (red[2] + red[3]);
  const float RESCALE_C = (float)(30720.0 * 0.6931471805599453);
  if (tid == 0) ll[b] = Lacc + __logf(tot) - RESCALE_C;
}

// ---------------- K5: final reduction ----------------
__global__ void k_final(const float* __restrict__ ll, float* __restrict__ out) {
  float v = ll[threadIdx.x];
  v = wave_sum64(v);
  if (threadIdx.x == 0) out[0] = -v;
}

extern "C" void kernel_launch(void* const* d_in, const int* in_sizes, int n_in,
                              void* d_out, int out_size, void* d_ws, size_t ws_size,
                              hipStream_t stream) {
  const int*   toks    = (const int*)d_in[0];
  const float* initlog = (const float*)d_in[1];
  const float* tag     = (const float*)d_in[2];
  const float* word    = (const float*)d_in[3];
  const float* bias    = (const float*)d_in[4];
  const float* q       = (const float*)d_in[5];
  const float* W       = (const float*)d_in[6];
  const float* tb      = (const float*)d_in[7];
  float* out = (float*)d_out;

  const int V = in_sizes[4];
  const int nPart = (V + 127) / 128;

  float* ws   = (float*)d_ws;
  float* E    = ws;
  float* pZ   = E + (size_t)V * KK;
  float* A2   = pZ + (size_t)nPart * KK;
  float* piZ  = A2 + KK * KK;
  float* piZP = piZ + KK;
  float* ll   = piZP + KK;
  unsigned* em = (unsigned*)(ll + BB);  // TT*BB*64 u32 = 32 MB

  const size_t floats_before_em =
      (size_t)V * KK + (size_t)nPart * KK + KK * KK + 2 * KK + BB;
  const size_t need = floats_before_em * 4 + (size_t)TT * BB * 64 * 4;

  k_emis <<<nPart, 128, 0, stream>>>(tag, word, bias, E, pZ, V);
  k_trans<<<KK, 128, 0, stream>>>(W, q, tb, pZ, initlog, A2, piZ, piZP, nPart);
  if (ws_size >= need) {
    k_gather<<<dim3(BB, TT / 32), 128, 0, stream>>>(toks, E, em);
    k_fwd_m3<<<2, 64, 0, stream>>>(em, A2, piZP, ll);
  } else {
    k_fwd_fb<<<BB, 256, 0, stream>>>(toks, E, A2, piZ, ll);
  }
  k_final<<<1, BB, 0, stream>>>(ll, out);
}

// Round 7
// 928.671 us; speedup vs baseline: 2.0512x; 2.0512x over previous
//
#include <hip/hip_runtime.h>

// Neural HMM forward-algorithm NLL.  K=128, V=50257, D=H=128, B=64, T=2048.
//
//  K1 k_emis : E[v][k] = exp(tag[k]·word[v] + bias[v]) (unnormalized) + partial Z
//  K2 k_trans: A2 (Z-folded, fallback), A2p = 128*softmax rows (fp8 path),
//              piZ (fallback), piZP = 128*softmax(init) permuted, ZinvP = V/Z_j permuted
//  K3 k_gather: em[t][b][p] = bf16( E[tok[b,t]][phi^-1(p)] * V/Z ), p = phi(j)
//  K4 k_fwd_m4: barrier-free MX-FP8 MFMA recursion, 1 wave per 16 batches.
//     mfma_scale_f32_16x16x128_f8f6f4: whole K=128 matvec in ONE MFMA ->
//     8 MFMA/step (277 pipe cyc) vs 32 bf16 MFMA (620). phi chosen so that
//     MFMA jt's D regs are exactly next step's B-operand word jt (lane-local):
//       phi: j = 16jt + 4g + r  ->  p = 32g + 4jt + r
//     A stored x128 (~1.0, fp8-friendly) with e8m0 scale 2^-7; Z-normalizer
//     folded into em so per-step factor ~1 and alpha stays ~1.0 (fp8 center).
//     True normalize every 64 steps; LL bookkeeping exact via RESCALE_C.
//  K5 k_final : out = -sum_b ll[b]

#define KK 128
#define TT 2048
#define BB 64

typedef int v8i __attribute__((ext_vector_type(8)));
typedef float v4f __attribute__((ext_vector_type(4)));

__device__ __forceinline__ float wave_sum64(float v) {
#pragma unroll
  for (int m = 32; m; m >>= 1) v += __shfl_xor(v, m, 64);
  return v;
}
__device__ __forceinline__ float wave_max64(float v) {
#pragma unroll
  for (int m = 32; m; m >>= 1) v = fmaxf(v, __shfl_xor(v, m, 64));
  return v;
}
// f32 -> bf16 round-to-nearest-even (positive normals here)
__device__ __forceinline__ unsigned short f2bf(float x) {
  union { float f; unsigned u; } c; c.f = x;
  unsigned r = c.u + 0x7fffu + ((c.u >> 16) & 1u);
  return (unsigned short)(r >> 16);
}
__device__ __forceinline__ float bflo(unsigned u) {
  union { unsigned u; float f; } c; c.u = u << 16; return c.f;
}
__device__ __forceinline__ float bfhi(unsigned u) {
  union { unsigned u; float f; } c; c.u = u & 0xffff0000u; return c.f;
}

// ---------------- K1: emission table E (V x K) + partial Z ----------------
__global__ __launch_bounds__(128, 1)
void k_emis(const float* __restrict__ tag, const float* __restrict__ word,
            const float* __restrict__ bias, float* __restrict__ E,
            float* __restrict__ partialZ, int V) {
  __shared__ float4 wtile[128 * 32];
  __shared__ float btile[128];
  const int tid = threadIdx.x;
  const int v0 = blockIdx.x * 128;

  const float4* w4 = (const float4*)word;
  const int maxi = V * 32 - 1;
#pragma unroll
  for (int it = 0; it < 32; ++it) {
    int idx = it * 128 + tid;
    int g = v0 * 32 + idx;
    wtile[idx] = w4[min(g, maxi)];
  }
  btile[tid] = (v0 + tid < V) ? bias[v0 + tid] : 0.f;

  float treg[128];
  const float4* t4 = (const float4*)(tag + (size_t)tid * 128);
#pragma unroll
  for (int c = 0; c < 32; ++c) {
    float4 x = t4[c];
    treg[4 * c + 0] = x.x; treg[4 * c + 1] = x.y;
    treg[4 * c + 2] = x.z; treg[4 * c + 3] = x.w;
  }
  __syncthreads();

  float zp = 0.f;
  for (int v = 0; v < 128; ++v) {
    if (v0 + v >= V) break;  // uniform
    const float4* row = &wtile[v * 32];
    float a0 = 0.f, a1 = 0.f, a2 = 0.f, a3 = 0.f;
#pragma unroll
    for (int c = 0; c < 32; ++c) {
      float4 pv = row[c];
      a0 = fmaf(pv.x, treg[4 * c + 0], a0);
      a1 = fmaf(pv.y, treg[4 * c + 1], a1);
      a2 = fmaf(pv.z, treg[4 * c + 2], a2);
      a3 = fmaf(pv.w, treg[4 * c + 3], a3);
    }
    float e = __expf((a0 + a1) + (a2 + a3) + btile[v]);
    E[(size_t)(v0 + v) * KK + tid] = e;
    zp += e;
  }
  partialZ[(size_t)blockIdx.x * KK + tid] = zp;
}

// ---------------- K2: transition matrix + piZ/piZP/ZinvP/A2p ----------
__global__ __launch_bounds__(128)
void k_trans(const float* __restrict__ W, const float* __restrict__ q,
             const float* __restrict__ tb, const float* __restrict__ pZ,
             const float* __restrict__ initlog, float* __restrict__ A2,
             float* __restrict__ A2p, float* __restrict__ piZ,
             float* __restrict__ piZP, float* __restrict__ ZinvP,
             int nPart, int V) {
  __shared__ float qs[KK];
  __shared__ float r0[2], r1[2];
  const int j = threadIdx.x, i = blockIdx.x;
  qs[j] = q[j];
  __syncthreads();

  const float4* w4 = (const float4*)(W + ((size_t)(i * KK + j)) * KK);
  const float4* q4 = (const float4*)qs;
  float a0 = 0.f, a1 = 0.f, a2 = 0.f, a3 = 0.f;
#pragma unroll
  for (int c = 0; c < KK / 4; ++c) {
    float4 wv = w4[c], qv = q4[c];
    a0 = fmaf(wv.x, qv.x, a0); a1 = fmaf(wv.y, qv.y, a1);
    a2 = fmaf(wv.z, qv.z, a2); a3 = fmaf(wv.w, qv.w, a3);
  }
  float logit = (a0 + a1) + (a2 + a3) + tb[i * KK + j];

  float m = wave_max64(logit);
  if ((j & 63) == 0) r0[j >> 6] = m;
  __syncthreads();
  m = fmaxf(r0[0], r0[1]);
  float e = __expf(logit - m);
  float s = wave_sum64(e);
  if ((j & 63) == 0) r1[j >> 6] = s;
  __syncthreads();
  s = r1[0] + r1[1];

  float Z0 = 0.f, Z1 = 0.f, Z2 = 0.f, Z3 = 0.f;
  float Z4 = 0.f, Z5 = 0.f, Z6 = 0.f, Z7 = 0.f;
  int p = 0;
  for (; p + 8 <= nPart; p += 8) {
    Z0 += pZ[(size_t)(p + 0) * KK + j]; Z1 += pZ[(size_t)(p + 1) * KK + j];
    Z2 += pZ[(size_t)(p + 2) * KK + j]; Z3 += pZ[(size_t)(p + 3) * KK + j];
    Z4 += pZ[(size_t)(p + 4) * KK + j]; Z5 += pZ[(size_t)(p + 5) * KK + j];
    Z6 += pZ[(size_t)(p + 6) * KK + j]; Z7 += pZ[(size_t)(p + 7) * KK + j];
  }
  for (; p < nPart; ++p) Z0 += pZ[(size_t)p * KK + j];
  float Z = ((Z0 + Z1) + (Z2 + Z3)) + ((Z4 + Z5) + (Z6 + Z7));

  A2[i * KK + j] = e / (s * Z);        // fallback path (Z-folded)
  A2p[i * KK + j] = 128.0f * e / s;    // fp8 path: pure softmax x128 (~1.0)

  if (i == 0) {
    float x = initlog[j];
    __syncthreads();
    float m2 = wave_max64(x);
    if ((j & 63) == 0) r0[j >> 6] = m2;
    __syncthreads();
    m2 = fmaxf(r0[0], r0[1]);
    float e2 = __expf(x - m2);
    float s2 = wave_sum64(e2);
    if ((j & 63) == 0) r1[j >> 6] = s2;
    __syncthreads();
    s2 = r1[0] + r1[1];
    piZ[j] = e2 / (s2 * Z);
    // phi: j = 16jt + 4g + r -> p = 32g + 4jt + r
    int pp = 32 * ((j >> 2) & 3) + 4 * (j >> 4) + (j & 3);
    piZP[pp] = 128.0f * e2 / s2;
    ZinvP[pp] = (float)V / Z;
  }
}

// ---------------- K3: em gather, PERMUTED layout, Z-fold ----------------
// em_u32[(t*BB+b)*64 + q] packs states p = 2q, 2q+1 as bf16 of E*V/Z.
// j(2q) = 16*((q>>1)&7) + 4*(q>>4) + 2*(q&1); float2 index = j(2q)/2.
__global__ __launch_bounds__(128, 1)
void k_gather(const int* __restrict__ toks, const float* __restrict__ E,
              const float* __restrict__ ZinvP, unsigned* __restrict__ em) {
  const int b = blockIdx.x;        // 0..63
  const int tc = blockIdx.y;       // 0..63 (32 t's each)
  const int q = threadIdx.x & 63;
  const int half = threadIdx.x >> 6;
  const int perm = 8 * ((q >> 1) & 7) + 2 * (q >> 4) + (q & 1);
  const float2 zi = ((const float2*)ZinvP)[q];
  const float2* E2 = (const float2*)E;
#pragma unroll 4
  for (int it = 0; it < 16; ++it) {
    int t = tc * 32 + it * 2 + half;
    int tok = toks[(size_t)b * TT + t];
    float2 v = E2[(size_t)tok * 64 + perm];
    unsigned lo = f2bf(v.x * zi.x), hi = f2bf(v.y * zi.y);
    em[((size_t)t * BB + b) * 64 + q] = lo | (hi << 16);
  }
}

// ---------------- K4: MX-FP8 K=128 single-wave recursion -----------------
// 4 blocks x 64 threads. lane l: m = l&15 (batch col / A row), g = l>>4.
// af[jt] byte e: A row i = 16*(e>>2) + 4g + (e&3), col j' = 16jt + m.
// B byte e = alphaP[32g + e]; D lane (m,g) reg r = alphaP'[32g + 4jt + r]
// = next B word jt bytes r. Scale: A x128 stored, e8m0 scale 120 (2^-7).
template <int S, bool LAST>
__device__ __forceinline__ void step8(int t, const uint4* __restrict__ emL,
                                      const v8i (&af)[8], v8i& bf,
                                      uint4 (&emQ)[4][4], float& Lacc,
                                      float (&nf)[8][4]) {
  const v4f ZED = {0.f, 0.f, 0.f, 0.f};
  const int SA = 0x78787878;  // e8m0 120 -> 2^-7 per 32-block (A stored x128)
  const int SB = 0x7f7f7f7f;  // e8m0 127 -> 1.0
  v4f acc[8];
#pragma unroll
  for (int jt = 0; jt < 8; ++jt)
    acc[jt] = __builtin_amdgcn_mfma_scale_f32_16x16x128_f8f6f4(
        af[jt], bf, ZED, 0, 0, 0, SA, 0, SB);

  uint4 ev[4];
#pragma unroll
  for (int kc = 0; kc < 4; ++kc) ev[kc] = emQ[S][kc];
  {
    int tp = (t + 4 < TT) ? (t + 4) : (TT - 1);
#pragma unroll
    for (int kc = 0; kc < 4; ++kc) emQ[S][kc] = emL[(size_t)tp * 1024 + kc];
  }

  float n[8][4];
#pragma unroll
  for (int jt = 0; jt < 8; ++jt) {
    uint4 w4 = ev[jt >> 1];
    unsigned c0 = (jt & 1) ? w4.z : w4.x;
    unsigned c1 = (jt & 1) ? w4.w : w4.y;
    n[jt][0] = acc[jt][0] * bflo(c0);
    n[jt][1] = acc[jt][1] * bfhi(c0);
    n[jt][2] = acc[jt][2] * bflo(c1);
    n[jt][3] = acc[jt][3] * bfhi(c1);
  }

  if ((t & 63) == 0) {  // true normalize to sum=128 (alpha mean 1.0)
    float sm = 0.f;
#pragma unroll
    for (int jt = 0; jt < 8; ++jt)
      sm += (n[jt][0] + n[jt][1]) + (n[jt][2] + n[jt][3]);
    sm += __shfl_xor(sm, 16, 64);
    sm += __shfl_xor(sm, 32, 64);
    float s128 = sm * 0.0078125f;
    float rc = __builtin_amdgcn_rcpf(s128);
    Lacc += __logf(s128);
#pragma unroll
    for (int jt = 0; jt < 8; ++jt) {
      n[jt][0] *= rc; n[jt][1] *= rc; n[jt][2] *= rc; n[jt][3] *= rc;
    }
  }

  if (LAST) {
#pragma unroll
    for (int jt = 0; jt < 8; ++jt)
#pragma unroll
      for (int r = 0; r < 4; ++r) nf[jt][r] = n[jt][r];
    return;
  }

#pragma unroll
  for (int jt = 0; jt < 8; ++jt) {
    int ww = __builtin_amdgcn_cvt_pk_fp8_f32(n[jt][0], n[jt][1], 0, false);
    ww = __builtin_amdgcn_cvt_pk_fp8_f32(n[jt][2], n[jt][3], ww, true);
    bf[jt] = ww;
  }
}

__global__ __launch_bounds__(64, 1)
void k_fwd_m4(const unsigned* __restrict__ em, const float* __restrict__ A2p,
              const float* __restrict__ piZP, float* __restrict__ ll, int V) {
  const int l = threadIdx.x;
  const int m = l & 15;
  const int g = l >> 4;
  const int gb = blockIdx.x * 16 + m;

  // static A fragments: 8 x v8i = 64 VGPRs of fp8
  v8i af[8];
#pragma unroll
  for (int jt = 0; jt < 8; ++jt) {
    const int colj = 16 * jt + m;
#pragma unroll
    for (int w = 0; w < 8; ++w) {
      const float* ap = A2p + (size_t)(16 * w + 4 * g) * KK + colj;
      int ww = __builtin_amdgcn_cvt_pk_fp8_f32(ap[0], ap[KK], 0, false);
      ww = __builtin_amdgcn_cvt_pk_fp8_f32(ap[2 * KK], ap[3 * KK], ww, true);
      af[jt][w] = ww;
    }
  }

  const uint4* emL = (const uint4*)(em + (size_t)gb * 64 + 16 * g);
  float Lacc = 0.f;

  // alpha0 = piZP * em0 -> initial B operand (fp8)
  v8i bf;
  {
    uint4 e0[4];
#pragma unroll
    for (int kc = 0; kc < 4; ++kc) e0[kc] = emL[kc];
#pragma unroll
    for (int jt = 0; jt < 8; ++jt) {
      float4 pz = *(const float4*)(piZP + 32 * g + 4 * jt);
      uint4 w4 = e0[jt >> 1];
      unsigned c0 = (jt & 1) ? w4.z : w4.x;
      unsigned c1 = (jt & 1) ? w4.w : w4.y;
      float n0 = pz.x * bflo(c0), n1 = pz.y * bfhi(c0);
      float n2 = pz.z * bflo(c1), n3 = pz.w * bfhi(c1);
      int ww = __builtin_amdgcn_cvt_pk_fp8_f32(n0, n1, 0, false);
      ww = __builtin_amdgcn_cvt_pk_fp8_f32(n2, n3, ww, true);
      bf[jt] = ww;
    }
  }

  // em prefetch, depth 4 (slot = t&3): preload t=1..4
  uint4 emQ[4][4];
#pragma unroll
  for (int tp = 1; tp <= 4; ++tp)
#pragma unroll
    for (int kc = 0; kc < 4; ++kc)
      emQ[tp & 3][kc] = emL[(size_t)tp * 1024 + kc];

  float nf[8][4];
  // t = 1..2044 in quads (S = t&3), then 2045, 2046, LAST 2047
  for (int c = 0; c < 511; ++c) {
    const int t0 = 1 + 4 * c;
    step8<1, false>(t0 + 0, emL, af, bf, emQ, Lacc, nf);
    step8<2, false>(t0 + 1, emL, af, bf, emQ, Lacc, nf);
    step8<3, false>(t0 + 2, emL, af, bf, emQ, Lacc, nf);
    step8<0, false>(t0 + 3, emL, af, bf, emQ, Lacc, nf);
  }
  step8<1, false>(TT - 3, emL, af, bf, emQ, Lacc, nf);
  step8<2, false>(TT - 2, emL, af, bf, emQ, Lacc, nf);
  step8<3, true >(TT - 1, emL, af, bf, emQ, Lacc, nf);

  float sm = 0.f;
#pragma unroll
  for (int jt = 0; jt < 8; ++jt)
    sm += (nf[jt][0] + nf[jt][1]) + (nf[jt][2] + nf[jt][3]);
  sm += __shfl_xor(sm, 16, 64);
  sm += __shfl_xor(sm, 32, 64);
  // folds: x(V/Z) per t (Z is the true model's emission normalizer, V the
  // fold constant: 2048 log V), init x128.
  const float RESCALE_C = (float)((double)TT * log((double)V) + log(128.0));
  if (l < 16) ll[blockIdx.x * 16 + l] = Lacc + __logf(sm) - RESCALE_C;
}

// ---------------- K4-fallback (round-3 path, used if ws too small) --------
__global__ __launch_bounds__(256, 1)
void k_fwd_fb(const int* __restrict__ toks, const float* __restrict__ E,
              const float* __restrict__ A2, const float* __restrict__ piZ,
              float* __restrict__ ll) {
  __shared__ float pb[2][KK];
  __shared__ float part[2 * KK];
  __shared__ int tk[TT];
  __shared__ float red[4];
  const int tid = threadIdx.x;
  const int j = tid & (KK - 1);
  const int h = tid >> 7;
  const int b = blockIdx.x;

  const int4* t4 = (const int4*)(toks + (size_t)b * TT);
  int4* l4 = (int4*)tk;
#pragma unroll
  for (int c = 0; c < TT / 4 / 256; ++c) l4[c * 256 + tid] = t4[c * 256 + tid];

  float Areg[64];
  {
    const float* Acol = A2 + (size_t)(h * 64) * KK + j;
#pragma unroll
    for (int i = 0; i < 64; ++i) Areg[i] = Acol[i * KK];
  }
  __syncthreads();

  const float* Ej = E + j;
  float eA = Ej[(size_t)tk[1] * KK];
  float eB = Ej[(size_t)tk[2] * KK];
  float eC = Ej[(size_t)tk[3] * KK];
  float eD = Ej[(size_t)tk[4] * KK];
  if (h == 0) pb[0][j] = piZ[j] * Ej[(size_t)tk[0] * KK];
  float Lacc = 0.f;
  __syncthreads();

  for (int t = 1; t < TT; ++t) {
    const float4* ph = (const float4*)&pb[(t - 1) & 1][h * 64];
    float a0 = 0.f, a1 = 0.f, a2 = 0.f, a3 = 0.f;
#pragma unroll
    for (int c = 0; c < 16; ++c) {
      float4 pv = ph[c];
      a0 = fmaf(pv.x, Areg[4 * c + 0], a0);
      a1 = fmaf(pv.y, Areg[4 * c + 1], a1);
      a2 = fmaf(pv.z, Areg[4 * c + 2], a2);
      a3 = fmaf(pv.w, Areg[4 * c + 3], a3);
    }
    part[2 * j + h] = (a0 + a1) + (a2 + a3);
    __syncthreads();

    float e = eA; eA = eB; eB = eC; eC = eD;
    int tn = tk[t + 4 < TT ? t + 4 : TT - 1];
    eD = Ej[(size_t)tn * KK];

    float np = 0.f;
    if (h == 0) {
      float2 pr = *(const float2*)&part[2 * j];
      np = (pr.x + pr.y) * e;
    }
    if ((t & 63) == 0) {
      float v = wave_sum64(np);
      if ((tid & 63) == 0) red[tid >> 6] = v;
      __syncthreads();
      float tot = (red[0] + red[1]) + (red[2] + red[3]);
      np *= __builtin_amdgcn_rcpf(tot);
      if (tid == 0) Lacc += __logf(tot);
    } else if ((t & 3) == 0) {
      np *= 0x1p64f;
    }
    if (h == 0) pb[t & 1][j] = np;
    __syncthreads();
  }

  float lv = (h == 0) ? pb[(TT - 1) & 1][j] : 0.f;
  float v = wave_sum64(lv);
  if ((tid & 63) == 0) red[tid >> 6] = v;
  __syncthreads();
  float tot = (red[0] + red[1]) + (red[2] + red[3]);
  const float RESCALE_C = (float)(30720.0 * 0.6931471805599453);
  if (tid == 0) ll[b] = Lacc + __logf(tot) - RESCALE_C;
}

// ---------------- K5: final reduction ----------------
__global__ void k_final(const float* __restrict__ ll, float* __restrict__ out) {
  float v = ll[threadIdx.x];
  v = wave_sum64(v);
  if (threadIdx.x == 0) out[0] = -v;
}

extern "C" void kernel_launch(void* const* d_in, const int* in_sizes, int n_in,
                              void* d_out, int out_size, void* d_ws, size_t ws_size,
                              hipStream_t stream) {
  const int*   toks    = (const int*)d_in[0];
  const float* initlog = (const float*)d_in[1];
  const float* tag     = (const float*)d_in[2];
  const float* word    = (const float*)d_in[3];
  const float* bias    = (const float*)d_in[4];
  const float* q       = (const float*)d_in[5];
  const float* W       = (const float*)d_in[6];
  const float* tb      = (const float*)d_in[7];
  float* out = (float*)d_out;

  const int V = in_sizes[4];
  const int nPart = (V + 127) / 128;

  float* ws    = (float*)d_ws;
  float* E     = ws;
  float* pZ    = E + (size_t)V * KK;
  float* A2    = pZ + (size_t)nPart * KK;
  float* A2p   = A2 + KK * KK;
  float* piZ   = A2p + KK * KK;
  float* piZP  = piZ + KK;
  float* ZinvP = piZP + KK;
  float* ll    = ZinvP + KK;
  unsigned* em = (unsigned*)(ll + BB);  // TT*BB*64 u32 = 32 MB

  const size_t floats_before_em =
      (size_t)V * KK + (size_t)nPart * KK + 2 * KK * KK + 3 * KK + BB;
  const size_t need = floats_before_em * 4 + (size_t)TT * BB * 64 * 4;

  k_emis <<<nPart, 128, 0, stream>>>(tag, word, bias, E, pZ, V);
  k_trans<<<KK, 128, 0, stream>>>(W, q, tb, pZ, initlog, A2, A2p, piZ, piZP,
                                  ZinvP, nPart, V);
  if (ws_size >= need) {
    k_gather<<<dim3(BB, TT / 32), 128, 0, stream>>>(toks, E, ZinvP, em);
    k_fwd_m4<<<4, 64, 0, stream>>>(em, A2p, piZP, ll, V);
  } else {
    k_fwd_fb<<<BB, 256, 0, stream>>>(toks, E, A2, piZ, ll);
  }
  k_final<<<1, BB, 0, stream>>>(ll, out);
}